// Round 4
// baseline (656.029 us; speedup 1.0000x reference)
//
#include <hip/hip_runtime.h>

// Luong dot attention, B=8, T=S=2048, D=1024, fp32 in/out.
// Fast path (ws >= 224 MiB):
//   P1: trg -> bf16 hi/lo;  P2: src -> bf16 hi/lo + fp16 transposed
//   G1: scores = trg @ src^T  bf16 3-pass, 32x32x16 MFMA, 256x128 tile
//   SM: softmax fp32 in place + fp16 weights (1 row/wave, 4 waves/block)
//   G2: context = w16 @ srcT16 fp16 32x32x16 MFMA, 256x128 tile
// Fallback = round-1 kernels.

#define BB 8
#define TT 2048
#define SS 2048
#define DD 1024

typedef float  f32x4   __attribute__((ext_vector_type(4)));
typedef float  f32x16  __attribute__((ext_vector_type(16)));
typedef short  bf16x8  __attribute__((ext_vector_type(8)));
typedef _Float16 f16x8 __attribute__((ext_vector_type(8)));
typedef _Float16 f16x4 __attribute__((ext_vector_type(4)));
typedef unsigned short u16x4 __attribute__((ext_vector_type(4)));

static __device__ __forceinline__ unsigned short bf16_rne(float x) {
  unsigned int u = __float_as_uint(x);
  u += 0x7FFFu + ((u >> 16) & 1u);
  return (unsigned short)(u >> 16);
}

static __device__ __forceinline__ void gl2lds16(const void* g, void* l) {
  __builtin_amdgcn_global_load_lds(
      (const __attribute__((address_space(1))) unsigned int*)g,
      (__attribute__((address_space(3))) unsigned int*)l, 16, 0, 0);
}

// ---------------------------------------------------------------------------
// P1: trg fp32 -> bf16 hi/lo.
// ---------------------------------------------------------------------------
__global__ __launch_bounds__(256)
void conv_hilo_trg(const float* __restrict__ x,
                   unsigned short* __restrict__ hi,
                   unsigned short* __restrict__ lo) {
  const size_t i = ((size_t)blockIdx.x * 256 + threadIdx.x) * 8;
  float4 v0 = *(const float4*)(x + i);
  float4 v1 = *(const float4*)(x + i + 4);
  float f[8] = {v0.x, v0.y, v0.z, v0.w, v1.x, v1.y, v1.z, v1.w};
  bf16x8 h, l;
#pragma unroll
  for (int e = 0; e < 8; ++e) {
    unsigned short hb = bf16_rne(f[e]);
    h[e] = (short)hb;
    float hf = __uint_as_float(((unsigned int)hb) << 16);
    l[e] = (short)bf16_rne(f[e] - hf);
  }
  *(bf16x8*)(hi + i) = h;
  *(bf16x8*)(lo + i) = l;
}

// ---------------------------------------------------------------------------
// P2: src fp32 -> bf16 hi/lo + fp16 transposed srcT[b][D][S].
// ---------------------------------------------------------------------------
__global__ __launch_bounds__(256)
void conv_src_hilo_t16(const float* __restrict__ src,
                       unsigned short* __restrict__ hi,
                       unsigned short* __restrict__ lo,
                       _Float16* __restrict__ srcT) {
  const int b  = blockIdx.z;
  const int d0 = blockIdx.x * 64;
  const int s0 = blockIdx.y * 64;
  const float* S = src + (size_t)b * SS * DD;
  __shared__ _Float16 t16[64][65];
  const int t = threadIdx.x;

#pragma unroll
  for (int p = 0; p < 4; ++p) {
    const int r = p * 16 + (t >> 4);
    const int c = (t & 15) * 4;
    float4 v = *(const float4*)(S + (size_t)(s0 + r) * DD + d0 + c);
    float f[4] = {v.x, v.y, v.z, v.w};
    u16x4 h, l;
#pragma unroll
    for (int e = 0; e < 4; ++e) {
      unsigned short hb = bf16_rne(f[e]);
      h[e] = hb;
      float hf = __uint_as_float(((unsigned int)hb) << 16);
      l[e] = bf16_rne(f[e] - hf);
      t16[r][c + e] = (_Float16)f[e];
    }
    const size_t go = ((size_t)b * SS + s0 + r) * DD + d0 + c;
    *(u16x4*)(hi + go) = h;
    *(u16x4*)(lo + go) = l;
  }
  __syncthreads();
#pragma unroll
  for (int p = 0; p < 4; ++p) {
    const int d  = p * 16 + (t >> 4);
    const int sq = (t & 15) * 4;
    f16x4 o;
#pragma unroll
    for (int k = 0; k < 4; ++k) o[k] = t16[sq + k][d];
    *(f16x4*)(srcT + ((size_t)b * DD + d0 + d) * SS + s0 + sq) = o;
  }
}

// ---------------------------------------------------------------------------
// G1: scores = trg @ src^T, bf16 3-pass, 256x128 tile, BK=32, 32x32x16 MFMA.
// Waves 2x2; wave-tile 128x64 (4x2 frags). XOR-swizzled gl2lds staging.
// ---------------------------------------------------------------------------
__global__ __launch_bounds__(256, 1)
void attn_gemm1_fat(const unsigned short* __restrict__ tH,
                    const unsigned short* __restrict__ tL,
                    const unsigned short* __restrict__ sH,
                    const unsigned short* __restrict__ sL,
                    float* __restrict__ scores) {
  const int b   = blockIdx.z;
  const int tm0 = blockIdx.y * 256;
  const int tn0 = blockIdx.x * 128;
  float* C = scores + (size_t)b * TT * SS;

  __shared__ __align__(16) unsigned short smAh[8192], smAl[8192];
  __shared__ __align__(16) unsigned short smBh[4096], smBl[4096];

  const int t      = threadIdx.x;
  const int lane   = t & 63;
  const int wv     = t >> 6;
  const int m_off  = (wv & 1) * 128;
  const int n_off  = (wv >> 1) * 64;
  const int lrow32 = lane & 31;
  const int khalf  = lane >> 5;

  // staging pointers: A has 1024 chunks (4/thread), B has 512 (2/thread)
  const unsigned short* pAh[4];
  const unsigned short* pAl[4];
  const unsigned short* pBh[2];
  const unsigned short* pBl[2];
#pragma unroll
  for (int h = 0; h < 4; ++h) {
    const int c = t + h * 256, r = c >> 2, g = (c & 3) ^ ((r >> 1) & 3);
    pAh[h] = tH + ((size_t)b * TT + tm0 + r) * DD + g * 8;
    pAl[h] = tL + ((size_t)b * TT + tm0 + r) * DD + g * 8;
  }
#pragma unroll
  for (int h = 0; h < 2; ++h) {
    const int c = t + h * 256, r = c >> 2, g = (c & 3) ^ ((r >> 1) & 3);
    pBh[h] = sH + ((size_t)b * SS + tn0 + r) * DD + g * 8;
    pBl[h] = sL + ((size_t)b * SS + tn0 + r) * DD + g * 8;
  }

  f32x16 acc[4][2];
#pragma unroll
  for (int i = 0; i < 4; ++i)
#pragma unroll
    for (int j = 0; j < 2; ++j) acc[i][j] = (f32x16)0.0f;

  for (int kt = 0; kt < DD; kt += 32) {
    __syncthreads();
#pragma unroll
    for (int h = 0; h < 4; ++h) {
      gl2lds16(pAh[h], smAh + (t + h * 256) * 8);
      gl2lds16(pAl[h], smAl + (t + h * 256) * 8);
      pAh[h] += 32; pAl[h] += 32;
    }
#pragma unroll
    for (int h = 0; h < 2; ++h) {
      gl2lds16(pBh[h], smBh + (t + h * 256) * 8);
      gl2lds16(pBl[h], smBl + (t + h * 256) * 8);
      pBh[h] += 32; pBl[h] += 32;
    }
    __syncthreads();

#pragma unroll
    for (int kk = 0; kk < 2; ++kk) {
      const int cb = kk * 2 + khalf;
      bf16x8 ah[4], al[4], bh[2], bl[2];
#pragma unroll
      for (int mi = 0; mi < 4; ++mi) {
        const int r   = m_off + mi * 32 + lrow32;
        const int off = (r * 4 + (cb ^ ((r >> 1) & 3))) * 8;
        ah[mi] = *(const bf16x8*)(smAh + off);
        al[mi] = *(const bf16x8*)(smAl + off);
      }
#pragma unroll
      for (int ni = 0; ni < 2; ++ni) {
        const int r   = n_off + ni * 32 + lrow32;
        const int off = (r * 4 + (cb ^ ((r >> 1) & 3))) * 8;
        bh[ni] = *(const bf16x8*)(smBh + off);
        bl[ni] = *(const bf16x8*)(smBl + off);
      }
#pragma unroll
      for (int mi = 0; mi < 4; ++mi)
#pragma unroll
        for (int ni = 0; ni < 2; ++ni) {
          acc[mi][ni] = __builtin_amdgcn_mfma_f32_32x32x16_bf16(al[mi], bh[ni], acc[mi][ni], 0, 0, 0);
          acc[mi][ni] = __builtin_amdgcn_mfma_f32_32x32x16_bf16(ah[mi], bl[ni], acc[mi][ni], 0, 0, 0);
          acc[mi][ni] = __builtin_amdgcn_mfma_f32_32x32x16_bf16(ah[mi], bh[ni], acc[mi][ni], 0, 0, 0);
        }
    }
  }

  // C/D 32x32: col=lane&31, row=(p&3)+8*(p>>2)+4*(lane>>5)
  const int rsub = 4 * khalf;
#pragma unroll
  for (int mi = 0; mi < 4; ++mi)
#pragma unroll
    for (int ni = 0; ni < 2; ++ni) {
      const int rb  = tm0 + m_off + mi * 32 + rsub;
      const int col = tn0 + n_off + ni * 32 + lrow32;
#pragma unroll
      for (int p = 0; p < 16; ++p)
        C[(size_t)(rb + (p & 3) + 8 * (p >> 2)) * SS + col] = acc[mi][ni][p];
    }
}

// ---------------------------------------------------------------------------
// SM: 4 waves/block, 1 row/wave, shuffle-only reduction, no barriers.
// ---------------------------------------------------------------------------
__global__ __launch_bounds__(256)
void attn_softmax_w16(float* __restrict__ w, _Float16* __restrict__ w16) {
  const size_t row = (size_t)blockIdx.x * 4 + (threadIdx.x >> 6);
  const int lane = threadIdx.x & 63;
  float4* p4 = (float4*)(w + row * SS);
  _Float16* o = w16 + row * SS;

  float4 v[8];
#pragma unroll
  for (int j = 0; j < 8; ++j) v[j] = p4[lane + 64 * j];

  float m = -1e30f;
#pragma unroll
  for (int j = 0; j < 8; ++j)
    m = fmaxf(m, fmaxf(fmaxf(v[j].x, v[j].y), fmaxf(v[j].z, v[j].w)));
#pragma unroll
  for (int off = 32; off >= 1; off >>= 1) m = fmaxf(m, __shfl_xor(m, off, 64));

  float s = 0.0f;
#pragma unroll
  for (int j = 0; j < 8; ++j) {
    v[j].x = __expf(v[j].x - m); v[j].y = __expf(v[j].y - m);
    v[j].z = __expf(v[j].z - m); v[j].w = __expf(v[j].w - m);
    s += v[j].x + v[j].y + v[j].z + v[j].w;
  }
#pragma unroll
  for (int off = 32; off >= 1; off >>= 1) s += __shfl_xor(s, off, 64);

  const float inv = __fdividef(1.0f, s);
#pragma unroll
  for (int j = 0; j < 8; ++j) {
    v[j].x *= inv; v[j].y *= inv; v[j].z *= inv; v[j].w *= inv;
    p4[lane + 64 * j] = v[j];
    f16x4 h;
    h[0] = (_Float16)v[j].x; h[1] = (_Float16)v[j].y;
    h[2] = (_Float16)v[j].z; h[3] = (_Float16)v[j].w;
    *(f16x4*)(o + 4 * (lane + 64 * j)) = h;
  }
}

// ---------------------------------------------------------------------------
// G2: context = w16 @ srcT16, fp16, 256x128 tile, BK=32, 32x32x16 MFMA.
// Waves 2x2; wave-tile 128x64 (4x2 frags).
// ---------------------------------------------------------------------------
__global__ __launch_bounds__(256, 1)
void attn_gemm2_fat(const _Float16* __restrict__ w16,
                    const _Float16* __restrict__ srcT,
                    float* __restrict__ out) {
  const int b   = blockIdx.z;
  const int tm0 = blockIdx.y * 256;  // T rows
  const int tn0 = blockIdx.x * 128;  // D cols
  float* C = out + (size_t)b * TT * DD;

  __shared__ __align__(16) _Float16 smA[8192], smB[4096];

  const int t      = threadIdx.x;
  const int lane   = t & 63;
  const int wv     = t >> 6;
  const int m_off  = (wv & 1) * 128;
  const int n_off  = (wv >> 1) * 64;
  const int lrow32 = lane & 31;
  const int khalf  = lane >> 5;

  const _Float16* pA[4];
  const _Float16* pB[2];
#pragma unroll
  for (int h = 0; h < 4; ++h) {
    const int c = t + h * 256, r = c >> 2, g = (c & 3) ^ ((r >> 1) & 3);
    pA[h] = w16 + ((size_t)b * TT + tm0 + r) * SS + g * 8;
  }
#pragma unroll
  for (int h = 0; h < 2; ++h) {
    const int c = t + h * 256, r = c >> 2, g = (c & 3) ^ ((r >> 1) & 3);
    pB[h] = srcT + ((size_t)b * DD + tn0 + r) * SS + g * 8;
  }

  f32x16 acc[4][2];
#pragma unroll
  for (int i = 0; i < 4; ++i)
#pragma unroll
    for (int j = 0; j < 2; ++j) acc[i][j] = (f32x16)0.0f;

  for (int kt = 0; kt < SS; kt += 32) {
    __syncthreads();
#pragma unroll
    for (int h = 0; h < 4; ++h) {
      gl2lds16(pA[h], smA + (t + h * 256) * 8);
      pA[h] += 32;
    }
#pragma unroll
    for (int h = 0; h < 2; ++h) {
      gl2lds16(pB[h], smB + (t + h * 256) * 8);
      pB[h] += 32;
    }
    __syncthreads();

#pragma unroll
    for (int kk = 0; kk < 2; ++kk) {
      const int cb = kk * 2 + khalf;
      f16x8 af[4], bf[2];
#pragma unroll
      for (int mi = 0; mi < 4; ++mi) {
        const int r   = m_off + mi * 32 + lrow32;
        const int off = (r * 4 + (cb ^ ((r >> 1) & 3))) * 8;
        af[mi] = *(const f16x8*)(smA + off);
      }
#pragma unroll
      for (int ni = 0; ni < 2; ++ni) {
        const int r   = n_off + ni * 32 + lrow32;
        const int off = (r * 4 + (cb ^ ((r >> 1) & 3))) * 8;
        bf[ni] = *(const f16x8*)(smB + off);
      }
#pragma unroll
      for (int mi = 0; mi < 4; ++mi)
#pragma unroll
        for (int ni = 0; ni < 2; ++ni)
          acc[mi][ni] = __builtin_amdgcn_mfma_f32_32x32x16_f16(af[mi], bf[ni], acc[mi][ni], 0, 0, 0);
    }
  }

  const int rsub = 4 * khalf;
#pragma unroll
  for (int mi = 0; mi < 4; ++mi)
#pragma unroll
    for (int ni = 0; ni < 2; ++ni) {
      const int rb  = tm0 + m_off + mi * 32 + rsub;
      const int col = tn0 + n_off + ni * 32 + lrow32;
#pragma unroll
      for (int p = 0; p < 16; ++p)
        C[(size_t)(rb + (p & 3) + 8 * (p >> 2)) * DD + col] = acc[mi][ni][p];
    }
}

// ===========================================================================
// Fallback path (round-1 kernels).
// ===========================================================================
__global__ __launch_bounds__(256, 1)
void attn_gemm1_scores_bf16x3(const float* __restrict__ trg,
                              const float* __restrict__ src,
                              float* __restrict__ scores) {
  const int b   = blockIdx.z;
  const int tm0 = blockIdx.y * 128;
  const int tn0 = blockIdx.x * 128;
  const float* A  = trg + (size_t)b * TT * DD;
  const float* Bm = src + (size_t)b * SS * DD;
  float* C = scores + (size_t)b * TT * SS;

  __shared__ __align__(16) unsigned short smAh[128 * 32];
  __shared__ __align__(16) unsigned short smAl[128 * 32];
  __shared__ __align__(16) unsigned short smBh[128 * 32];
  __shared__ __align__(16) unsigned short smBl[128 * 32];

  const int t     = threadIdx.x;
  const int lane  = t & 63;
  const int wv    = t >> 6;
  const int m_off = (wv & 1) * 64;
  const int n_off = (wv >> 1) * 64;
  const int q     = lane >> 4;
  const int lrow  = lane & 15;

  f32x4 acc[4][4];
#pragma unroll
  for (int i = 0; i < 4; ++i)
#pragma unroll
    for (int j = 0; j < 4; ++j) acc[i][j] = (f32x4)0.0f;

  for (int kt = 0; kt < DD; kt += 32) {
    __syncthreads();
#pragma unroll
    for (int h = 0; h < 2; ++h) {
      const int c  = t + h * 256;
      const int r  = c >> 2;
      const int j  = c & 3;
      const int gk = j ^ ((r >> 1) & 3);
      {
        const float* ga = A + (size_t)(tm0 + r) * DD + kt + gk * 8;
        float4 v0 = *(const float4*)ga;
        float4 v1 = *(const float4*)(ga + 4);
        float f[8] = {v0.x, v0.y, v0.z, v0.w, v1.x, v1.y, v1.z, v1.w};
        bf16x8 hi, lo;
#pragma unroll
        for (int e = 0; e < 8; ++e) {
          unsigned short hb = bf16_rne(f[e]);
          hi[e] = (short)hb;
          float hf = __uint_as_float(((unsigned int)hb) << 16);
          lo[e] = (short)bf16_rne(f[e] - hf);
        }
        *(bf16x8*)(smAh + c * 8) = hi;
        *(bf16x8*)(smAl + c * 8) = lo;
      }
      {
        const float* gb = Bm + (size_t)(tn0 + r) * DD + kt + gk * 8;
        float4 v0 = *(const float4*)gb;
        float4 v1 = *(const float4*)(gb + 4);
        float f[8] = {v0.x, v0.y, v0.z, v0.w, v1.x, v1.y, v1.z, v1.w};
        bf16x8 hi, lo;
#pragma unroll
        for (int e = 0; e < 8; ++e) {
          unsigned short hb = bf16_rne(f[e]);
          hi[e] = (short)hb;
          float hf = __uint_as_float(((unsigned int)hb) << 16);
          lo[e] = (short)bf16_rne(f[e] - hf);
        }
        *(bf16x8*)(smBh + c * 8) = hi;
        *(bf16x8*)(smBl + c * 8) = lo;
      }
    }
    __syncthreads();

    bf16x8 ah[4], al[4], bh[4], bl[4];
#pragma unroll
    for (int mi = 0; mi < 4; ++mi) {
      const int r   = m_off + mi * 16 + lrow;
      const int off = (r * 4 + (q ^ ((r >> 1) & 3))) * 8;
      ah[mi] = *(const bf16x8*)(smAh + off);
      al[mi] = *(const bf16x8*)(smAl + off);
    }
#pragma unroll
    for (int ni = 0; ni < 4; ++ni) {
      const int r   = n_off + ni * 16 + lrow;
      const int off = (r * 4 + (q ^ ((r >> 1) & 3))) * 8;
      bh[ni] = *(const bf16x8*)(smBh + off);
      bl[ni] = *(const bf16x8*)(smBl + off);
    }
#pragma unroll
    for (int mi = 0; mi < 4; ++mi)
#pragma unroll
      for (int ni = 0; ni < 4; ++ni) {
        acc[mi][ni] = __builtin_amdgcn_mfma_f32_16x16x32_bf16(al[mi], bh[ni], acc[mi][ni], 0, 0, 0);
        acc[mi][ni] = __builtin_amdgcn_mfma_f32_16x16x32_bf16(ah[mi], bl[ni], acc[mi][ni], 0, 0, 0);
        acc[mi][ni] = __builtin_amdgcn_mfma_f32_16x16x32_bf16(ah[mi], bh[ni], acc[mi][ni], 0, 0, 0);
      }
  }

#pragma unroll
  for (int mi = 0; mi < 4; ++mi)
#pragma unroll
    for (int ni = 0; ni < 4; ++ni) {
      const int row0 = tm0 + m_off + mi * 16 + q * 4;
      const int col  = tn0 + n_off + ni * 16 + lrow;
#pragma unroll
      for (int p = 0; p < 4; ++p)
        C[(size_t)(row0 + p) * SS + col] = acc[mi][ni][p];
    }
}

__global__ __launch_bounds__(256)
void attn_softmax_rows(float* __restrict__ w) {
  float* p = w + (size_t)blockIdx.x * SS;
  const int t = threadIdx.x;
  float4* p4 = (float4*)p;
  float4 v0 = p4[t];
  float4 v1 = p4[t + 256];

  float m = fmaxf(fmaxf(fmaxf(v0.x, v0.y), fmaxf(v0.z, v0.w)),
                  fmaxf(fmaxf(v1.x, v1.y), fmaxf(v1.z, v1.w)));
#pragma unroll
  for (int off = 32; off >= 1; off >>= 1) m = fmaxf(m, __shfl_xor(m, off, 64));
  __shared__ float redm[4];
  __shared__ float reds[4];
  const int wv = t >> 6, lane = t & 63;
  if (lane == 0) redm[wv] = m;
  __syncthreads();
  m = fmaxf(fmaxf(redm[0], redm[1]), fmaxf(redm[2], redm[3]));

  v0.x = __expf(v0.x - m); v0.y = __expf(v0.y - m);
  v0.z = __expf(v0.z - m); v0.w = __expf(v0.w - m);
  v1.x = __expf(v1.x - m); v1.y = __expf(v1.y - m);
  v1.z = __expf(v1.z - m); v1.w = __expf(v1.w - m);

  float s = v0.x + v0.y + v0.z + v0.w + v1.x + v1.y + v1.z + v1.w;
#pragma unroll
  for (int off = 32; off >= 1; off >>= 1) s += __shfl_xor(s, off, 64);
  if (lane == 0) reds[wv] = s;
  __syncthreads();
  s = reds[0] + reds[1] + reds[2] + reds[3];

  const float inv = __fdividef(1.0f, s);
  v0.x *= inv; v0.y *= inv; v0.z *= inv; v0.w *= inv;
  v1.x *= inv; v1.y *= inv; v1.z *= inv; v1.w *= inv;
  p4[t] = v0;
  p4[t + 256] = v1;
}

__global__ __launch_bounds__(256, 1)
void attn_gemm2_ctx_f16(const float* __restrict__ w,
                        const float* __restrict__ src,
                        float* __restrict__ out) {
  const int b   = blockIdx.z;
  const int tm0 = blockIdx.y * 128;
  const int tn0 = blockIdx.x * 128;
  const float* A  = w + (size_t)b * TT * SS;
  const float* Bs = src + (size_t)b * SS * DD;
  float* C = out + (size_t)b * TT * DD;

  __shared__ __align__(16) _Float16 smA[128 * 32];
  __shared__ __align__(16) _Float16 smB[128 * 32];

  const int t     = threadIdx.x;
  const int lane  = t & 63;
  const int wv    = t >> 6;
  const int m_off = (wv & 1) * 64;
  const int n_off = (wv >> 1) * 64;
  const int q     = lane >> 4;
  const int lrow  = lane & 15;

  const int bn    = t & 127;
  const int bh2   = t >> 7;
  const int bs2   = (bn >> 1) & 3;
  const int slot0 = (2 * bh2) ^ bs2;
  const int slot1 = (2 * bh2 + 1) ^ bs2;

  f32x4 acc[4][4];
#pragma unroll
  for (int i = 0; i < 4; ++i)
#pragma unroll
    for (int j = 0; j < 4; ++j) acc[i][j] = (f32x4)0.0f;

  for (int kt = 0; kt < SS; kt += 32) {
    __syncthreads();
#pragma unroll
    for (int h = 0; h < 2; ++h) {
      const int c  = t + h * 256;
      const int r  = c >> 2;
      const int j  = c & 3;
      const int gk = j ^ ((r >> 1) & 3);
      const float* ga = A + (size_t)(tm0 + r) * SS + kt + gk * 8;
      float4 v0 = *(const float4*)ga;
      float4 v1 = *(const float4*)(ga + 4);
      f16x8 hv;
      hv[0] = (_Float16)v0.x; hv[1] = (_Float16)v0.y;
      hv[2] = (_Float16)v0.z; hv[3] = (_Float16)v0.w;
      hv[4] = (_Float16)v1.x; hv[5] = (_Float16)v1.y;
      hv[6] = (_Float16)v1.z; hv[7] = (_Float16)v1.w;
      *(f16x8*)(smA + c * 8) = hv;
    }
    {
      const float* gb = Bs + (size_t)(kt + bh2 * 16) * DD + (tn0 + bn);
      f16x8 c0, c1;
#pragma unroll
      for (int kk = 0; kk < 8; ++kk) c0[kk] = (_Float16)gb[(size_t)kk * DD];
#pragma unroll
      for (int kk = 0; kk < 8; ++kk) c1[kk] = (_Float16)gb[(size_t)(kk + 8) * DD];
      *(f16x8*)(smB + bn * 32 + slot0 * 8) = c0;
      *(f16x8*)(smB + bn * 32 + slot1 * 8) = c1;
    }
    __syncthreads();

    f16x8 af[4], bfr[4];
#pragma unroll
    for (int mi = 0; mi < 4; ++mi) {
      const int r   = m_off + mi * 16 + lrow;
      const int off = (r * 4 + (q ^ ((r >> 1) & 3))) * 8;
      af[mi] = *(const f16x8*)(smA + off);
    }
#pragma unroll
    for (int ni = 0; ni < 4; ++ni) {
      const int n   = n_off + ni * 16 + lrow;
      const int off = n * 32 + (q ^ ((n >> 1) & 3)) * 8;
      bfr[ni] = *(const f16x8*)(smB + off);
    }
#pragma unroll
    for (int mi = 0; mi < 4; ++mi)
#pragma unroll
      for (int ni = 0; ni < 4; ++ni)
        acc[mi][ni] = __builtin_amdgcn_mfma_f32_16x16x32_f16(af[mi], bfr[ni], acc[mi][ni], 0, 0, 0);
  }

#pragma unroll
  for (int mi = 0; mi < 4; ++mi)
#pragma unroll
    for (int ni = 0; ni < 4; ++ni) {
      const int row0 = tm0 + m_off + mi * 16 + q * 4;
      const int col  = tn0 + n_off + ni * 16 + lrow;
#pragma unroll
      for (int p = 0; p < 4; ++p)
        C[(size_t)(row0 + p) * DD + col] = acc[mi][ni][p];
    }
}

extern "C" void kernel_launch(void* const* d_in, const int* in_sizes, int n_in,
                              void* d_out, int out_size, void* d_ws, size_t ws_size,
                              hipStream_t stream) {
  const float* trg = (const float*)d_in[0];
  const float* src = (const float*)d_in[1];
  float* ctx = (float*)d_out;
  float* wts = (float*)d_out + (size_t)BB * TT * DD;

  const size_t NT = (size_t)BB * TT * DD;
  const size_t NW = (size_t)BB * TT * SS;
  const size_t need = (5 * NT + NW) * 2;  // 224 MiB

  if (ws_size >= need) {
    unsigned short* tH = (unsigned short*)d_ws;
    unsigned short* tL = tH + NT;
    unsigned short* sH = tL + NT;
    unsigned short* sL = sH + NT;
    _Float16* srcT = (_Float16*)(sL + NT);
    _Float16* w16  = srcT + NT;

    conv_hilo_trg<<<dim3(NT / (8 * 256)), 256, 0, stream>>>(trg, tH, tL);
    conv_src_hilo_t16<<<dim3(DD / 64, SS / 64, BB), 256, 0, stream>>>(src, sH, sL, srcT);
    attn_gemm1_fat<<<dim3(SS / 128, TT / 256, BB), 256, 0, stream>>>(tH, tL, sH, sL, wts);
    attn_softmax_w16<<<dim3(BB * TT / 4), 256, 0, stream>>>(wts, w16);
    attn_gemm2_fat<<<dim3(DD / 128, TT / 256, BB), 256, 0, stream>>>(w16, srcT, ctx);
  } else {
    attn_gemm1_scores_bf16x3<<<dim3(SS / 128, TT / 128, BB), 256, 0, stream>>>(trg, src, wts);
    attn_softmax_rows<<<dim3(BB * TT), 256, 0, stream>>>(wts);
    attn_gemm2_ctx_f16<<<dim3(DD / 128, TT / 128, BB), 256, 0, stream>>>(wts, src, ctx);
  }
}

// Round 5
// 594.939 us; speedup vs baseline: 1.1027x; 1.1027x over previous
//
#include <hip/hip_runtime.h>

// Luong dot attention, B=8, T=S=2048, D=1024, fp32 in/out.
// Fast path (ws >= 192 MiB):
//   P1: trg -> fp16
//   P2: src -> fp16 hi + fp16 lo + fp16 transposed (hi)
//   G1: scores = trg16 @ (srcHi+srcLo)^T  fp16 2-pass, 32x32x16 MFMA, 128x128
//   SM: softmax fp32 in place + fp16 weights (single-wave blocks)
//   G2: context = w16 @ srcT16 fp16 32x32x16 MFMA, 128x128 (R3-measured best)
// Fallback = round-1 kernels.

#define BB 8
#define TT 2048
#define SS 2048
#define DD 1024

typedef float  f32x4   __attribute__((ext_vector_type(4)));
typedef float  f32x16  __attribute__((ext_vector_type(16)));
typedef short  bf16x8  __attribute__((ext_vector_type(8)));
typedef _Float16 f16x8 __attribute__((ext_vector_type(8)));
typedef _Float16 f16x4 __attribute__((ext_vector_type(4)));

static __device__ __forceinline__ unsigned short bf16_rne(float x) {
  unsigned int u = __float_as_uint(x);
  u += 0x7FFFu + ((u >> 16) & 1u);
  return (unsigned short)(u >> 16);
}

static __device__ __forceinline__ void gl2lds16(const void* g, void* l) {
  __builtin_amdgcn_global_load_lds(
      (const __attribute__((address_space(1))) unsigned int*)g,
      (__attribute__((address_space(3))) unsigned int*)l, 16, 0, 0);
}

// ---------------------------------------------------------------------------
// P1: trg fp32 -> fp16 (single).
// ---------------------------------------------------------------------------
__global__ __launch_bounds__(256)
void conv_trg_f16(const float* __restrict__ x, _Float16* __restrict__ h16) {
  const size_t i = ((size_t)blockIdx.x * 256 + threadIdx.x) * 8;
  float4 v0 = *(const float4*)(x + i);
  float4 v1 = *(const float4*)(x + i + 4);
  f16x8 h;
  h[0] = (_Float16)v0.x; h[1] = (_Float16)v0.y;
  h[2] = (_Float16)v0.z; h[3] = (_Float16)v0.w;
  h[4] = (_Float16)v1.x; h[5] = (_Float16)v1.y;
  h[6] = (_Float16)v1.z; h[7] = (_Float16)v1.w;
  *(f16x8*)(h16 + i) = h;
}

// ---------------------------------------------------------------------------
// P2: src fp32 -> fp16 hi + fp16 lo ([S][D]) + fp16 transposed hi ([D][S]).
// lo = fp16(src - (float)hi): may be denormal for tiny src — negligible error.
// ---------------------------------------------------------------------------
__global__ __launch_bounds__(256)
void conv_src_f16_hilo_t(const float* __restrict__ src,
                         _Float16* __restrict__ hi,
                         _Float16* __restrict__ lo,
                         _Float16* __restrict__ srcT) {
  const int b  = blockIdx.z;
  const int d0 = blockIdx.x * 64;
  const int s0 = blockIdx.y * 64;
  const float* S = src + (size_t)b * SS * DD;
  __shared__ _Float16 t16[64][65];
  const int t = threadIdx.x;

#pragma unroll
  for (int p = 0; p < 4; ++p) {
    const int r = p * 16 + (t >> 4);
    const int c = (t & 15) * 4;
    float4 v = *(const float4*)(S + (size_t)(s0 + r) * DD + d0 + c);
    float f[4] = {v.x, v.y, v.z, v.w};
    f16x4 h, l;
#pragma unroll
    for (int e = 0; e < 4; ++e) {
      _Float16 hv = (_Float16)f[e];
      h[e] = hv;
      l[e] = (_Float16)(f[e] - (float)hv);
      t16[r][c + e] = hv;
    }
    const size_t go = ((size_t)b * SS + s0 + r) * DD + d0 + c;
    *(f16x4*)(hi + go) = h;
    *(f16x4*)(lo + go) = l;
  }
  __syncthreads();
#pragma unroll
  for (int p = 0; p < 4; ++p) {
    const int d  = p * 16 + (t >> 4);
    const int sq = (t & 15) * 4;
    f16x4 o;
#pragma unroll
    for (int k = 0; k < 4; ++k) o[k] = t16[sq + k][d];
    *(f16x4*)(srcT + ((size_t)b * DD + d0 + d) * SS + s0 + sq) = o;
  }
}

// ---------------------------------------------------------------------------
// G1: scores = trg16 @ src16^T, fp16 2-pass (A single, B hi+lo), 128x128 tile,
// BK=32, 32x32x16 MFMA, XOR-swizzled gl2lds staging (R3 structure).
// ---------------------------------------------------------------------------
__global__ __launch_bounds__(256, 1)
void attn_gemm1_2p(const _Float16* __restrict__ a16,
                   const _Float16* __restrict__ bh16,
                   const _Float16* __restrict__ bl16,
                   float* __restrict__ scores) {
  const int b   = blockIdx.z;
  const int tm0 = blockIdx.y * 128;
  const int tn0 = blockIdx.x * 128;
  float* C = scores + (size_t)b * TT * SS;

  __shared__ __align__(16) _Float16 smA[4096];
  __shared__ __align__(16) _Float16 smBh[4096], smBl[4096];

  const int t      = threadIdx.x;
  const int lane   = t & 63;
  const int wv     = t >> 6;
  const int m_off  = (wv & 1) * 64;
  const int n_off  = (wv >> 1) * 64;
  const int lrow32 = lane & 31;
  const int khalf  = lane >> 5;

  const int s0 = t, s1 = t + 256;
  const int r0 = s0 >> 2, g0 = (s0 & 3) ^ ((r0 >> 1) & 3);
  const int r1 = s1 >> 2, g1 = (s1 & 3) ^ ((r1 >> 1) & 3);

  const _Float16* pA0 = a16 + ((size_t)b * TT + tm0 + r0) * DD + g0 * 8;
  const _Float16* pA1 = a16 + ((size_t)b * TT + tm0 + r1) * DD + g1 * 8;
  const _Float16* pBh0 = bh16 + ((size_t)b * SS + tn0 + r0) * DD + g0 * 8;
  const _Float16* pBh1 = bh16 + ((size_t)b * SS + tn0 + r1) * DD + g1 * 8;
  const _Float16* pBl0 = bl16 + ((size_t)b * SS + tn0 + r0) * DD + g0 * 8;
  const _Float16* pBl1 = bl16 + ((size_t)b * SS + tn0 + r1) * DD + g1 * 8;

  f32x16 acc[2][2];
#pragma unroll
  for (int i = 0; i < 2; ++i)
#pragma unroll
    for (int j = 0; j < 2; ++j) acc[i][j] = (f32x16)0.0f;

  for (int kt = 0; kt < DD; kt += 32) {
    __syncthreads();
    gl2lds16(pA0, smA + s0 * 8);  gl2lds16(pA1, smA + s1 * 8);
    gl2lds16(pBh0, smBh + s0 * 8); gl2lds16(pBh1, smBh + s1 * 8);
    gl2lds16(pBl0, smBl + s0 * 8); gl2lds16(pBl1, smBl + s1 * 8);
    pA0 += 32; pA1 += 32; pBh0 += 32; pBh1 += 32; pBl0 += 32; pBl1 += 32;
    __syncthreads();

#pragma unroll
    for (int kk = 0; kk < 2; ++kk) {
      const int cb = kk * 2 + khalf;
      f16x8 a[2], bh[2], bl[2];
#pragma unroll
      for (int mi = 0; mi < 2; ++mi) {
        const int r   = m_off + mi * 32 + lrow32;
        const int off = (r * 4 + (cb ^ ((r >> 1) & 3))) * 8;
        a[mi] = *(const f16x8*)(smA + off);
      }
#pragma unroll
      for (int ni = 0; ni < 2; ++ni) {
        const int r   = n_off + ni * 32 + lrow32;
        const int off = (r * 4 + (cb ^ ((r >> 1) & 3))) * 8;
        bh[ni] = *(const f16x8*)(smBh + off);
        bl[ni] = *(const f16x8*)(smBl + off);
      }
#pragma unroll
      for (int mi = 0; mi < 2; ++mi)
#pragma unroll
        for (int ni = 0; ni < 2; ++ni) {
          acc[mi][ni] = __builtin_amdgcn_mfma_f32_32x32x16_f16(a[mi], bh[ni], acc[mi][ni], 0, 0, 0);
          acc[mi][ni] = __builtin_amdgcn_mfma_f32_32x32x16_f16(a[mi], bl[ni], acc[mi][ni], 0, 0, 0);
        }
    }
  }

  // C/D 32x32: col=lane&31, row=(p&3)+8*(p>>2)+4*(lane>>5)
  const int rsub = 4 * khalf;
#pragma unroll
  for (int mi = 0; mi < 2; ++mi)
#pragma unroll
    for (int ni = 0; ni < 2; ++ni) {
      const int rb  = tm0 + m_off + mi * 32 + rsub;
      const int col = tn0 + n_off + ni * 32 + lrow32;
#pragma unroll
      for (int p = 0; p < 16; ++p)
        C[(size_t)(rb + (p & 3) + 8 * (p >> 2)) * SS + col] = acc[mi][ni][p];
    }
}

// ---------------------------------------------------------------------------
// SM: single-wave blocks (R3-measured). 32 floats/lane, shuffle-only.
// ---------------------------------------------------------------------------
__global__ __launch_bounds__(64)
void attn_softmax_w16(float* __restrict__ w, _Float16* __restrict__ w16) {
  const size_t row = blockIdx.x;
  float4* p4 = (float4*)(w + row * SS);
  _Float16* o = w16 + row * SS;
  const int lane = threadIdx.x;

  float4 v[8];
#pragma unroll
  for (int j = 0; j < 8; ++j) v[j] = p4[lane + 64 * j];

  float m = -1e30f;
#pragma unroll
  for (int j = 0; j < 8; ++j)
    m = fmaxf(m, fmaxf(fmaxf(v[j].x, v[j].y), fmaxf(v[j].z, v[j].w)));
#pragma unroll
  for (int off = 32; off >= 1; off >>= 1) m = fmaxf(m, __shfl_xor(m, off, 64));

  float s = 0.0f;
#pragma unroll
  for (int j = 0; j < 8; ++j) {
    v[j].x = __expf(v[j].x - m); v[j].y = __expf(v[j].y - m);
    v[j].z = __expf(v[j].z - m); v[j].w = __expf(v[j].w - m);
    s += v[j].x + v[j].y + v[j].z + v[j].w;
  }
#pragma unroll
  for (int off = 32; off >= 1; off >>= 1) s += __shfl_xor(s, off, 64);

  const float inv = __fdividef(1.0f, s);
#pragma unroll
  for (int j = 0; j < 8; ++j) {
    v[j].x *= inv; v[j].y *= inv; v[j].z *= inv; v[j].w *= inv;
    p4[lane + 64 * j] = v[j];
    f16x4 h;
    h[0] = (_Float16)v[j].x; h[1] = (_Float16)v[j].y;
    h[2] = (_Float16)v[j].z; h[3] = (_Float16)v[j].w;
    *(f16x4*)(o + 4 * (lane + 64 * j)) = h;
  }
}

// ---------------------------------------------------------------------------
// G2: context = w16 @ srcT16, fp16 32x32x16 MFMA, 128x128 tile (R3-measured).
// ---------------------------------------------------------------------------
__global__ __launch_bounds__(256, 1)
void attn_gemm2_fast32(const _Float16* __restrict__ w16,
                       const _Float16* __restrict__ srcT,
                       float* __restrict__ out) {
  const int b   = blockIdx.z;
  const int tm0 = blockIdx.y * 128;
  const int tn0 = blockIdx.x * 128;
  float* C = out + (size_t)b * TT * DD;

  __shared__ __align__(16) _Float16 smA[4096], smB[4096];

  const int t      = threadIdx.x;
  const int lane   = t & 63;
  const int wv     = t >> 6;
  const int m_off  = (wv & 1) * 64;
  const int n_off  = (wv >> 1) * 64;
  const int lrow32 = lane & 31;
  const int khalf  = lane >> 5;

  const int s0 = t, s1 = t + 256;
  const int r0 = s0 >> 2, g0 = (s0 & 3) ^ ((r0 >> 1) & 3);
  const int r1 = s1 >> 2, g1 = (s1 & 3) ^ ((r1 >> 1) & 3);

  const _Float16* pA0 = w16 + ((size_t)b * TT + tm0 + r0) * SS + g0 * 8;
  const _Float16* pA1 = w16 + ((size_t)b * TT + tm0 + r1) * SS + g1 * 8;
  const _Float16* pB0 = srcT + ((size_t)b * DD + tn0 + r0) * SS + g0 * 8;
  const _Float16* pB1 = srcT + ((size_t)b * DD + tn0 + r1) * SS + g1 * 8;

  f32x16 acc[2][2];
#pragma unroll
  for (int i = 0; i < 2; ++i)
#pragma unroll
    for (int j = 0; j < 2; ++j) acc[i][j] = (f32x16)0.0f;

  for (int kt = 0; kt < SS; kt += 32) {
    __syncthreads();
    gl2lds16(pA0, smA + s0 * 8); gl2lds16(pA1, smA + s1 * 8);
    gl2lds16(pB0, smB + s0 * 8); gl2lds16(pB1, smB + s1 * 8);
    pA0 += 32; pA1 += 32; pB0 += 32; pB1 += 32;
    __syncthreads();

#pragma unroll
    for (int kk = 0; kk < 2; ++kk) {
      const int cb = kk * 2 + khalf;
      f16x8 af[2], bf[2];
#pragma unroll
      for (int mi = 0; mi < 2; ++mi) {
        const int r   = m_off + mi * 32 + lrow32;
        const int off = (r * 4 + (cb ^ ((r >> 1) & 3))) * 8;
        af[mi] = *(const f16x8*)(smA + off);
      }
#pragma unroll
      for (int ni = 0; ni < 2; ++ni) {
        const int r   = n_off + ni * 32 + lrow32;
        const int off = (r * 4 + (cb ^ ((r >> 1) & 3))) * 8;
        bf[ni] = *(const f16x8*)(smB + off);
      }
#pragma unroll
      for (int mi = 0; mi < 2; ++mi)
#pragma unroll
        for (int ni = 0; ni < 2; ++ni)
          acc[mi][ni] = __builtin_amdgcn_mfma_f32_32x32x16_f16(af[mi], bf[ni], acc[mi][ni], 0, 0, 0);
    }
  }

  const int rsub = 4 * khalf;
#pragma unroll
  for (int mi = 0; mi < 2; ++mi)
#pragma unroll
    for (int ni = 0; ni < 2; ++ni) {
      const int rb  = tm0 + m_off + mi * 32 + rsub;
      const int col = tn0 + n_off + ni * 32 + lrow32;
#pragma unroll
      for (int p = 0; p < 16; ++p)
        C[(size_t)(rb + (p & 3) + 8 * (p >> 2)) * DD + col] = acc[mi][ni][p];
    }
}

// ===========================================================================
// Fallback path (round-1 kernels, no workspace).
// ===========================================================================
__global__ __launch_bounds__(256, 1)
void attn_gemm1_scores_bf16x3(const float* __restrict__ trg,
                              const float* __restrict__ src,
                              float* __restrict__ scores) {
  const int b   = blockIdx.z;
  const int tm0 = blockIdx.y * 128;
  const int tn0 = blockIdx.x * 128;
  const float* A  = trg + (size_t)b * TT * DD;
  const float* Bm = src + (size_t)b * SS * DD;
  float* C = scores + (size_t)b * TT * SS;

  __shared__ __align__(16) unsigned short smAh[128 * 32];
  __shared__ __align__(16) unsigned short smAl[128 * 32];
  __shared__ __align__(16) unsigned short smBh[128 * 32];
  __shared__ __align__(16) unsigned short smBl[128 * 32];

  const int t     = threadIdx.x;
  const int lane  = t & 63;
  const int wv    = t >> 6;
  const int m_off = (wv & 1) * 64;
  const int n_off = (wv >> 1) * 64;
  const int q     = lane >> 4;
  const int lrow  = lane & 15;

  f32x4 acc[4][4];
#pragma unroll
  for (int i = 0; i < 4; ++i)
#pragma unroll
    for (int j = 0; j < 4; ++j) acc[i][j] = (f32x4)0.0f;

  for (int kt = 0; kt < DD; kt += 32) {
    __syncthreads();
#pragma unroll
    for (int h = 0; h < 2; ++h) {
      const int c  = t + h * 256;
      const int r  = c >> 2;
      const int j  = c & 3;
      const int gk = j ^ ((r >> 1) & 3);
      {
        const float* ga = A + (size_t)(tm0 + r) * DD + kt + gk * 8;
        float4 v0 = *(const float4*)ga;
        float4 v1 = *(const float4*)(ga + 4);
        float f[8] = {v0.x, v0.y, v0.z, v0.w, v1.x, v1.y, v1.z, v1.w};
        bf16x8 hi, lo;
#pragma unroll
        for (int e = 0; e < 8; ++e) {
          unsigned short hb = bf16_rne(f[e]);
          hi[e] = (short)hb;
          float hf = __uint_as_float(((unsigned int)hb) << 16);
          lo[e] = (short)bf16_rne(f[e] - hf);
        }
        *(bf16x8*)(smAh + c * 8) = hi;
        *(bf16x8*)(smAl + c * 8) = lo;
      }
      {
        const float* gb = Bm + (size_t)(tn0 + r) * DD + kt + gk * 8;
        float4 v0 = *(const float4*)gb;
        float4 v1 = *(const float4*)(gb + 4);
        float f[8] = {v0.x, v0.y, v0.z, v0.w, v1.x, v1.y, v1.z, v1.w};
        bf16x8 hi, lo;
#pragma unroll
        for (int e = 0; e < 8; ++e) {
          unsigned short hb = bf16_rne(f[e]);
          hi[e] = (short)hb;
          float hf = __uint_as_float(((unsigned int)hb) << 16);
          lo[e] = (short)bf16_rne(f[e] - hf);
        }
        *(bf16x8*)(smBh + c * 8) = hi;
        *(bf16x8*)(smBl + c * 8) = lo;
      }
    }
    __syncthreads();

    bf16x8 ah[4], al[4], bh[4], bl[4];
#pragma unroll
    for (int mi = 0; mi < 4; ++mi) {
      const int r   = m_off + mi * 16 + lrow;
      const int off = (r * 4 + (q ^ ((r >> 1) & 3))) * 8;
      ah[mi] = *(const bf16x8*)(smAh + off);
      al[mi] = *(const bf16x8*)(smAl + off);
    }
#pragma unroll
    for (int ni = 0; ni < 4; ++ni) {
      const int r   = n_off + ni * 16 + lrow;
      const int off = (r * 4 + (q ^ ((r >> 1) & 3))) * 8;
      bh[ni] = *(const bf16x8*)(smBh + off);
      bl[ni] = *(const bf16x8*)(smBl + off);
    }
#pragma unroll
    for (int mi = 0; mi < 4; ++mi)
#pragma unroll
      for (int ni = 0; ni < 4; ++ni) {
        acc[mi][ni] = __builtin_amdgcn_mfma_f32_16x16x32_bf16(al[mi], bh[ni], acc[mi][ni], 0, 0, 0);
        acc[mi][ni] = __builtin_amdgcn_mfma_f32_16x16x32_bf16(ah[mi], bl[ni], acc[mi][ni], 0, 0, 0);
        acc[mi][ni] = __builtin_amdgcn_mfma_f32_16x16x32_bf16(ah[mi], bh[ni], acc[mi][ni], 0, 0, 0);
      }
  }

#pragma unroll
  for (int mi = 0; mi < 4; ++mi)
#pragma unroll
    for (int ni = 0; ni < 4; ++ni) {
      const int row0 = tm0 + m_off + mi * 16 + q * 4;
      const int col  = tn0 + n_off + ni * 16 + lrow;
#pragma unroll
      for (int p = 0; p < 4; ++p)
        C[(size_t)(row0 + p) * SS + col] = acc[mi][ni][p];
    }
}

__global__ __launch_bounds__(256)
void attn_softmax_rows(float* __restrict__ w) {
  float* p = w + (size_t)blockIdx.x * SS;
  const int t = threadIdx.x;
  float4* p4 = (float4*)p;
  float4 v0 = p4[t];
  float4 v1 = p4[t + 256];

  float m = fmaxf(fmaxf(fmaxf(v0.x, v0.y), fmaxf(v0.z, v0.w)),
                  fmaxf(fmaxf(v1.x, v1.y), fmaxf(v1.z, v1.w)));
#pragma unroll
  for (int off = 32; off >= 1; off >>= 1) m = fmaxf(m, __shfl_xor(m, off, 64));
  __shared__ float redm[4];
  __shared__ float reds[4];
  const int wv = t >> 6, lane = t & 63;
  if (lane == 0) redm[wv] = m;
  __syncthreads();
  m = fmaxf(fmaxf(redm[0], redm[1]), fmaxf(redm[2], redm[3]));

  v0.x = __expf(v0.x - m); v0.y = __expf(v0.y - m);
  v0.z = __expf(v0.z - m); v0.w = __expf(v0.w - m);
  v1.x = __expf(v1.x - m); v1.y = __expf(v1.y - m);
  v1.z = __expf(v1.z - m); v1.w = __expf(v1.w - m);

  float s = v0.x + v0.y + v0.z + v0.w + v1.x + v1.y + v1.z + v1.w;
#pragma unroll
  for (int off = 32; off >= 1; off >>= 1) s += __shfl_xor(s, off, 64);
  if (lane == 0) reds[wv] = s;
  __syncthreads();
  s = reds[0] + reds[1] + reds[2] + reds[3];

  const float inv = __fdividef(1.0f, s);
  v0.x *= inv; v0.y *= inv; v0.z *= inv; v0.w *= inv;
  v1.x *= inv; v1.y *= inv; v1.z *= inv; v1.w *= inv;
  p4[t] = v0;
  p4[t + 256] = v1;
}

__global__ __launch_bounds__(256, 1)
void attn_gemm2_ctx_f16(const float* __restrict__ w,
                        const float* __restrict__ src,
                        float* __restrict__ out) {
  const int b   = blockIdx.z;
  const int tm0 = blockIdx.y * 128;
  const int tn0 = blockIdx.x * 128;
  const float* A  = w + (size_t)b * TT * SS;
  const float* Bs = src + (size_t)b * SS * DD;
  float* C = out + (size_t)b * TT * DD;

  __shared__ __align__(16) _Float16 smA[128 * 32];
  __shared__ __align__(16) _Float16 smB[128 * 32];

  const int t     = threadIdx.x;
  const int lane  = t & 63;
  const int wv    = t >> 6;
  const int m_off = (wv & 1) * 64;
  const int n_off = (wv >> 1) * 64;
  const int q     = lane >> 4;
  const int lrow  = lane & 15;

  const int bn    = t & 127;
  const int bh2   = t >> 7;
  const int bs2   = (bn >> 1) & 3;
  const int slot0 = (2 * bh2) ^ bs2;
  const int slot1 = (2 * bh2 + 1) ^ bs2;

  f32x4 acc[4][4];
#pragma unroll
  for (int i = 0; i < 4; ++i)
#pragma unroll
    for (int j = 0; j < 4; ++j) acc[i][j] = (f32x4)0.0f;

  for (int kt = 0; kt < SS; kt += 32) {
    __syncthreads();
#pragma unroll
    for (int h = 0; h < 2; ++h) {
      const int c  = t + h * 256;
      const int r  = c >> 2;
      const int j  = c & 3;
      const int gk = j ^ ((r >> 1) & 3);
      const float* ga = A + (size_t)(tm0 + r) * SS + kt + gk * 8;
      float4 v0 = *(const float4*)ga;
      float4 v1 = *(const float4*)(ga + 4);
      f16x8 hv;
      hv[0] = (_Float16)v0.x; hv[1] = (_Float16)v0.y;
      hv[2] = (_Float16)v0.z; hv[3] = (_Float16)v0.w;
      hv[4] = (_Float16)v1.x; hv[5] = (_Float16)v1.y;
      hv[6] = (_Float16)v1.z; hv[7] = (_Float16)v1.w;
      *(f16x8*)(smA + c * 8) = hv;
    }
    {
      const float* gb = Bs + (size_t)(kt + bh2 * 16) * DD + (tn0 + bn);
      f16x8 c0, c1;
#pragma unroll
      for (int kk = 0; kk < 8; ++kk) c0[kk] = (_Float16)gb[(size_t)kk * DD];
#pragma unroll
      for (int kk = 0; kk < 8; ++kk) c1[kk] = (_Float16)gb[(size_t)(kk + 8) * DD];
      *(f16x8*)(smB + bn * 32 + slot0 * 8) = c0;
      *(f16x8*)(smB + bn * 32 + slot1 * 8) = c1;
    }
    __syncthreads();

    f16x8 af[4], bfr[4];
#pragma unroll
    for (int mi = 0; mi < 4; ++mi) {
      const int r   = m_off + mi * 16 + lrow;
      const int off = (r * 4 + (q ^ ((r >> 1) & 3))) * 8;
      af[mi] = *(const f16x8*)(smA + off);
    }
#pragma unroll
    for (int ni = 0; ni < 4; ++ni) {
      const int n   = n_off + ni * 16 + lrow;
      const int off = n * 32 + (q ^ ((n >> 1) & 3)) * 8;
      bfr[ni] = *(const f16x8*)(smB + off);
    }
#pragma unroll
    for (int mi = 0; mi < 4; ++mi)
#pragma unroll
      for (int ni = 0; ni < 4; ++ni)
        acc[mi][ni] = __builtin_amdgcn_mfma_f32_16x16x32_f16(af[mi], bfr[ni], acc[mi][ni], 0, 0, 0);
  }

#pragma unroll
  for (int mi = 0; mi < 4; ++mi)
#pragma unroll
    for (int ni = 0; ni < 4; ++ni) {
      const int row0 = tm0 + m_off + mi * 16 + q * 4;
      const int col  = tn0 + n_off + ni * 16 + lrow;
#pragma unroll
      for (int p = 0; p < 4; ++p)
        C[(size_t)(row0 + p) * DD + col] = acc[mi][ni][p];
    }
}

extern "C" void kernel_launch(void* const* d_in, const int* in_sizes, int n_in,
                              void* d_out, int out_size, void* d_ws, size_t ws_size,
                              hipStream_t stream) {
  const float* trg = (const float*)d_in[0];
  const float* src = (const float*)d_in[1];
  float* ctx = (float*)d_out;
  float* wts = (float*)d_out + (size_t)BB * TT * DD;

  const size_t NT = (size_t)BB * TT * DD;  // 16,777,216
  const size_t NW = (size_t)BB * TT * SS;  // 33,554,432
  const size_t need = (4 * NT + NW) * 2;   // 201,326,592 B = 192 MiB

  if (ws_size >= need) {
    _Float16* tH16 = (_Float16*)d_ws;
    _Float16* sH16 = tH16 + NT;
    _Float16* sL16 = sH16 + NT;
    _Float16* srcT = sL16 + NT;
    _Float16* w16  = srcT + NT;

    conv_trg_f16<<<dim3(NT / (8 * 256)), 256, 0, stream>>>(trg, tH16);
    conv_src_f16_hilo_t<<<dim3(DD / 64, SS / 64, BB), 256, 0, stream>>>(src, sH16, sL16, srcT);
    attn_gemm1_2p<<<dim3(SS / 128, TT / 128, BB), 256, 0, stream>>>(tH16, sH16, sL16, wts);
    attn_softmax_w16<<<dim3(BB * TT), 64, 0, stream>>>(wts, w16);
    attn_gemm2_fast32<<<dim3(DD / 128, TT / 128, BB), 256, 0, stream>>>(w16, srcT, ctx);
  } else {
    attn_gemm1_scores_bf16x3<<<dim3(SS / 128, TT / 128, BB), 256, 0, stream>>>(trg, src, wts);
    attn_softmax_rows<<<dim3(BB * TT), 256, 0, stream>>>(wts);
    attn_gemm2_ctx_f16<<<dim3(DD / 128, TT / 128, BB), 256, 0, stream>>>(wts, src, ctx);
  }
}